// Round 3
// baseline (1931.844 us; speedup 1.0000x reference)
//
#include <hip/hip_runtime.h>
#include <math.h>

#define BATCH 4096
#define NODES 256
#define FDIM  128
#define HID   16
#define WSTR  20   // LDS W row stride (floats): 80B keeps float4 align, breaks bank alias

// One block per batch element b; 256 threads = 4 waves.
// Mapping: 4 lanes per node-row (q = lane&3 owns f-quarter), 16 rows per wave
// per pass, 4 passes. x loads are fully line-coalesced: instruction j reads
// float4-slot 4j+q of each of 16 rows -> 16 complete 64B lines per instr.
// Weights Ab[t] (8KB) staged once into padded LDS, read as broadcast b128.
__launch_bounds__(256, 4)
__global__ void mta_kernel(const float* __restrict__ x,
                           const float* __restrict__ a1,
                           const float* __restrict__ a2,
                           const float* __restrict__ adj,
                           const int*  __restrict__ node_index,
                           const int*  __restrict__ type_index,
                           float* __restrict__ out) {
    const int b    = blockIdx.x;
    const int tid  = threadIdx.x;
    const int lane = tid & 63;
    const int w    = tid >> 6;
    const int q    = lane & 3;   // f-quarter within row
    const int rl   = lane >> 2;  // row within 16-row group

    __shared__ __align__(16) float lw[FDIM * WSTR];  // 10.25 KB padded W
    __shared__ float es[NODES];
    __shared__ float part[16][17];
    __shared__ float c0s[HID];
    __shared__ float redm[4], reds[4];

    const int t  = __builtin_amdgcn_readfirstlane(type_index[b]);
    const int ni = __builtin_amdgcn_readfirstlane(node_index[0]);

    const float* At  = a1 + (size_t)t * (2 * FDIM * HID); // top    [FDIM][HID]
    const float* Ab  = At + FDIM * HID;                   // bottom [FDIM][HID]
    const float* a2t = a2 + t * HID;
    const float* xb  = x + (size_t)b * NODES * FDIM;

    // ---- stage W = Ab into padded LDS (512 float4s, 2 per thread) ----
    {
        const float4* Ab4 = (const float4*)Ab;
        #pragma unroll
        for (int i = 0; i < 2; ++i) {
            const int idx = tid * 2 + i;          // 0..511
            const int f   = idx >> 2;
            const int c   = idx & 3;
            *(float4*)&lw[f * WSTR + c * 4] = Ab4[idx];
        }
    }

    // ---- c0[h] = sum_f x[b,ni,f] * At[f][h] (cooperative) ----
    {
        const float* x0 = xb + (size_t)ni * FDIM;
        const int f2 = tid >> 4;   // 16 f-groups of 8
        const int h  = tid & 15;
        float p = 0.f;
        #pragma unroll
        for (int j = 0; j < 8; ++j) {
            const int f = f2 * 8 + j;
            p = fmaf(x0[f], At[f * HID + h], p);
        }
        part[f2][h] = p;
    }
    __syncthreads();
    if (tid < 16) {
        float s = 0.f;
        #pragma unroll
        for (int g = 0; g < 16; ++g) s += part[g][tid];
        c0s[tid] = s;
    }
    __syncthreads();   // lw + c0s ready

    // ---- main: 4 passes x 16 rows per wave, no barriers ----
    #pragma unroll 1
    for (int p = 0; p < 4; ++p) {
        const int row = w * 64 + p * 16 + rl;
        const float* xr = xb + (size_t)row * FDIM;

        float4 xv[8];
        #pragma unroll
        for (int j = 0; j < 8; ++j)
            xv[j] = *(const float4*)(xr + (4 * j + q) * 4);  // coalesced lines

        float acc[16];
        #pragma unroll
        for (int h = 0; h < 16; ++h) acc[h] = 0.f;

        #pragma unroll
        for (int j = 0; j < 8; ++j) {
            #pragma unroll
            for (int k = 0; k < 4; ++k) {
                const int f = 16 * j + 4 * q + k;   // this lane's f for comp k
                const float xk = (k == 0) ? xv[j].x : (k == 1) ? xv[j].y
                               : (k == 2) ? xv[j].z : xv[j].w;
                const float4 w0 = *(const float4*)&lw[f * WSTR + 0];
                const float4 w1 = *(const float4*)&lw[f * WSTR + 4];
                const float4 w2 = *(const float4*)&lw[f * WSTR + 8];
                const float4 w3 = *(const float4*)&lw[f * WSTR + 12];
                acc[0]  = fmaf(xk, w0.x, acc[0]);
                acc[1]  = fmaf(xk, w0.y, acc[1]);
                acc[2]  = fmaf(xk, w0.z, acc[2]);
                acc[3]  = fmaf(xk, w0.w, acc[3]);
                acc[4]  = fmaf(xk, w1.x, acc[4]);
                acc[5]  = fmaf(xk, w1.y, acc[5]);
                acc[6]  = fmaf(xk, w1.z, acc[6]);
                acc[7]  = fmaf(xk, w1.w, acc[7]);
                acc[8]  = fmaf(xk, w2.x, acc[8]);
                acc[9]  = fmaf(xk, w2.y, acc[9]);
                acc[10] = fmaf(xk, w2.z, acc[10]);
                acc[11] = fmaf(xk, w2.w, acc[11]);
                acc[12] = fmaf(xk, w3.x, acc[12]);
                acc[13] = fmaf(xk, w3.y, acc[13]);
                acc[14] = fmaf(xk, w3.z, acc[14]);
                acc[15] = fmaf(xk, w3.w, acc[15]);
            }
        }

        // reduce across the 4 q-lanes (2 butterfly stages)
        #pragma unroll
        for (int h = 0; h < 16; ++h) {
            acc[h] += __shfl_xor(acc[h], 1);
            acc[h] += __shfl_xor(acc[h], 2);
        }

        // e = lrelu( sum_h lrelu(acc+c0) * a2 )
        float e = 0.f;
        #pragma unroll
        for (int h = 0; h < 16; ++h) {
            float v = acc[h] + c0s[h];
            v = (v > 0.f) ? v : 0.01f * v;
            e = fmaf(v, a2t[h], e);
        }
        e = (e > 0.f) ? e : 0.01f * e;

        if (q == 0) es[row] = e;
    }
    __syncthreads();

    // ---- masked softmax over 256 nodes ----
    const float e   = es[tid];
    const float m   = adj[tid];
    float       val = (m > 0.f) ? e : -INFINITY;

    float mx = val;
    #pragma unroll
    for (int off = 32; off; off >>= 1) mx = fmaxf(mx, __shfl_xor(mx, off));
    const int wid = tid >> 6;
    if ((tid & 63) == 0) redm[wid] = mx;
    __syncthreads();
    mx = fmaxf(fmaxf(redm[0], redm[1]), fmaxf(redm[2], redm[3]));

    float pr = (m > 0.f) ? __expf(e - mx) : 0.f;
    float s = pr;
    #pragma unroll
    for (int off = 32; off; off >>= 1) s += __shfl_xor(s, off);
    if ((tid & 63) == 0) reds[wid] = s;
    __syncthreads();
    const float Z = reds[0] + reds[1] + reds[2] + reds[3];

    out[(size_t)b * NODES + tid] = pr / Z;
}

extern "C" void kernel_launch(void* const* d_in, const int* in_sizes, int n_in,
                              void* d_out, int out_size, void* d_ws, size_t ws_size,
                              hipStream_t stream) {
    const float* x   = (const float*)d_in[0];
    const float* a1  = (const float*)d_in[1];
    const float* a2  = (const float*)d_in[2];
    const float* adj = (const float*)d_in[3];
    const int*   ni  = (const int*)d_in[4];
    const int*   ti  = (const int*)d_in[5];
    float* out = (float*)d_out;

    mta_kernel<<<BATCH, NODES, 0, stream>>>(x, a1, a2, adj, ni, ti, out);
}

// Round 4
// 434.120 us; speedup vs baseline: 4.4500x; 4.4500x over previous
//
#include <hip/hip_runtime.h>
#include <math.h>

#define BATCH 4096
#define NODES 256
#define FDIM  128
#define HID   16
#define WSTR  20   // LDS W row stride (floats): 80B keeps float4 align, breaks bank alias

// One block per batch element b; 256 threads = 4 waves.
// Mapping: 4 lanes per node-row (q = lane&3 owns an f-quarter), 16 rows per
// wave per pass, 4 passes. x loads are fully line-coalesced: instruction j
// reads float4-slot 4j+q of each of 16 rows -> 16 complete 64B lines/instr
// (same line count as a contiguous 1KB wave load).
// Weights Ab[t] (8KB) staged once into padded LDS, read as broadcast b128.
//
// NOTE: no min-waves arg in __launch_bounds__ — on this toolchain
// __launch_bounds__(256,4) capped VGPR at 64 (empirical cap ~256/w) and the
// ~85-reg live set spilled to scratch: 1.8GB writes, 3.9GB fetch, 11x slow.
__launch_bounds__(256)
__global__ void mta_kernel(const float* __restrict__ x,
                           const float* __restrict__ a1,
                           const float* __restrict__ a2,
                           const float* __restrict__ adj,
                           const int*  __restrict__ node_index,
                           const int*  __restrict__ type_index,
                           float* __restrict__ out) {
    const int b    = blockIdx.x;
    const int tid  = threadIdx.x;
    const int lane = tid & 63;
    const int w    = tid >> 6;
    const int q    = lane & 3;   // f-quarter within row
    const int rl   = lane >> 2;  // row within 16-row group

    __shared__ __align__(16) float lw[FDIM * WSTR];  // 10.25 KB padded W
    __shared__ float es[NODES];
    __shared__ float part[16][17];
    __shared__ float c0s[HID];
    __shared__ float redm[4], reds[4];

    const int t  = __builtin_amdgcn_readfirstlane(type_index[b]);
    const int ni = __builtin_amdgcn_readfirstlane(node_index[0]);

    const float* At  = a1 + (size_t)t * (2 * FDIM * HID); // top    [FDIM][HID]
    const float* Ab  = At + FDIM * HID;                   // bottom [FDIM][HID]
    const float* a2t = a2 + t * HID;
    const float* xb  = x + (size_t)b * NODES * FDIM;

    // ---- stage W = Ab into padded LDS (512 float4s, 2 per thread) ----
    {
        const float4* Ab4 = (const float4*)Ab;
        #pragma unroll
        for (int i = 0; i < 2; ++i) {
            const int idx = tid * 2 + i;          // 0..511
            const int f   = idx >> 2;
            const int c   = idx & 3;
            *(float4*)&lw[f * WSTR + c * 4] = Ab4[idx];
        }
    }

    // ---- c0[h] = sum_f x[b,ni,f] * At[f][h] (cooperative) ----
    {
        const float* x0 = xb + (size_t)ni * FDIM;
        const int f2 = tid >> 4;   // 16 f-groups of 8
        const int h  = tid & 15;
        float p = 0.f;
        #pragma unroll
        for (int j = 0; j < 8; ++j) {
            const int f = f2 * 8 + j;
            p = fmaf(x0[f], At[f * HID + h], p);
        }
        part[f2][h] = p;
    }
    __syncthreads();
    if (tid < 16) {
        float s = 0.f;
        #pragma unroll
        for (int g = 0; g < 16; ++g) s += part[g][tid];
        c0s[tid] = s;
    }
    __syncthreads();   // lw + c0s ready

    // ---- main: 4 passes x 16 rows per wave, no barriers ----
    #pragma unroll 1
    for (int p = 0; p < 4; ++p) {
        const int row = w * 64 + p * 16 + rl;
        const float* xr = xb + (size_t)row * FDIM;

        float4 xv[8];
        #pragma unroll
        for (int j = 0; j < 8; ++j)
            xv[j] = *(const float4*)(xr + (4 * j + q) * 4);  // coalesced lines

        float acc[16];
        #pragma unroll
        for (int h = 0; h < 16; ++h) acc[h] = 0.f;

        #pragma unroll
        for (int j = 0; j < 8; ++j) {
            #pragma unroll
            for (int k = 0; k < 4; ++k) {
                const int f = 16 * j + 4 * q + k;   // this lane's f for comp k
                const float xk = (k == 0) ? xv[j].x : (k == 1) ? xv[j].y
                               : (k == 2) ? xv[j].z : xv[j].w;
                const float4 w0 = *(const float4*)&lw[f * WSTR + 0];
                const float4 w1 = *(const float4*)&lw[f * WSTR + 4];
                const float4 w2 = *(const float4*)&lw[f * WSTR + 8];
                const float4 w3 = *(const float4*)&lw[f * WSTR + 12];
                acc[0]  = fmaf(xk, w0.x, acc[0]);
                acc[1]  = fmaf(xk, w0.y, acc[1]);
                acc[2]  = fmaf(xk, w0.z, acc[2]);
                acc[3]  = fmaf(xk, w0.w, acc[3]);
                acc[4]  = fmaf(xk, w1.x, acc[4]);
                acc[5]  = fmaf(xk, w1.y, acc[5]);
                acc[6]  = fmaf(xk, w1.z, acc[6]);
                acc[7]  = fmaf(xk, w1.w, acc[7]);
                acc[8]  = fmaf(xk, w2.x, acc[8]);
                acc[9]  = fmaf(xk, w2.y, acc[9]);
                acc[10] = fmaf(xk, w2.z, acc[10]);
                acc[11] = fmaf(xk, w2.w, acc[11]);
                acc[12] = fmaf(xk, w3.x, acc[12]);
                acc[13] = fmaf(xk, w3.y, acc[13]);
                acc[14] = fmaf(xk, w3.z, acc[14]);
                acc[15] = fmaf(xk, w3.w, acc[15]);
            }
        }

        // reduce across the 4 q-lanes (2 butterfly stages)
        #pragma unroll
        for (int h = 0; h < 16; ++h) {
            acc[h] += __shfl_xor(acc[h], 1);
            acc[h] += __shfl_xor(acc[h], 2);
        }

        // e = lrelu( sum_h lrelu(acc+c0) * a2 )
        float e = 0.f;
        #pragma unroll
        for (int h = 0; h < 16; ++h) {
            float v = acc[h] + c0s[h];
            v = (v > 0.f) ? v : 0.01f * v;
            e = fmaf(v, a2t[h], e);
        }
        e = (e > 0.f) ? e : 0.01f * e;

        if (q == 0) es[row] = e;
    }
    __syncthreads();

    // ---- masked softmax over 256 nodes ----
    const float e   = es[tid];
    const float m   = adj[tid];
    float       val = (m > 0.f) ? e : -INFINITY;

    float mx = val;
    #pragma unroll
    for (int off = 32; off; off >>= 1) mx = fmaxf(mx, __shfl_xor(mx, off));
    const int wid = tid >> 6;
    if ((tid & 63) == 0) redm[wid] = mx;
    __syncthreads();
    mx = fmaxf(fmaxf(redm[0], redm[1]), fmaxf(redm[2], redm[3]));

    float pr = (m > 0.f) ? __expf(e - mx) : 0.f;
    float s = pr;
    #pragma unroll
    for (int off = 32; off; off >>= 1) s += __shfl_xor(s, off);
    if ((tid & 63) == 0) reds[wid] = s;
    __syncthreads();
    const float Z = reds[0] + reds[1] + reds[2] + reds[3];

    out[(size_t)b * NODES + tid] = pr / Z;
}

extern "C" void kernel_launch(void* const* d_in, const int* in_sizes, int n_in,
                              void* d_out, int out_size, void* d_ws, size_t ws_size,
                              hipStream_t stream) {
    const float* x   = (const float*)d_in[0];
    const float* a1  = (const float*)d_in[1];
    const float* a2  = (const float*)d_in[2];
    const float* adj = (const float*)d_in[3];
    const int*   ni  = (const int*)d_in[4];
    const int*   ti  = (const int*)d_in[5];
    float* out = (float*)d_out;

    mta_kernel<<<BATCH, NODES, 0, stream>>>(x, a1, a2, adj, ni, ti, out);
}

// Round 5
// 180.824 us; speedup vs baseline: 10.6836x; 2.4008x over previous
//
#include <hip/hip_runtime.h>
#include <math.h>

#define BATCH 4096
#define NODES 256
#define FDIM  128
#define HID   16
#define CHF   16                  // floats per f-chunk
#define NCHK  (FDIM / CHF)        // 8 chunks

// One block per batch element b; 256 threads = 4 waves; wave w owns rows
// 64w..64w+63; lane owns row 64w+lane for COMPUTE (so every lane processes
// the same (f,h) at the same time -> weights are wave-uniform -> s_load/SGPR,
// zero LDS/VALU cost for W; this was round-1's winning weight path).
// x is fixed by a wave-private LDS transpose: stage f-chunks coalesced
// (16 full 64B lines per instruction), read back per-lane-row, XOR-swizzled
// (slot = f4 ^ (row&3)) so b128 reads/writes hit banks at floor rate.
// Double-buffered per wave, NO block barriers in the main loop.
// __launch_bounds__(256,2): empirical VGPR cap = 256/min_waves -> 128.
__launch_bounds__(256, 2)
__global__ void mta_kernel(const float* __restrict__ x,
                           const float* __restrict__ a1,
                           const float* __restrict__ a2,
                           const float* __restrict__ adj,
                           const int*  __restrict__ node_index,
                           const int*  __restrict__ type_index,
                           float* __restrict__ out) {
    const int b    = blockIdx.x;
    const int tid  = threadIdx.x;
    const int lane = tid & 63;
    const int w    = tid >> 6;

    // per (wave, parity) 64 rows x 16 floats = 4KB; 8 areas = 32KB
    __shared__ __align__(16) float xl[8][64 * CHF];
    __shared__ float es[NODES];
    __shared__ float part[16][17];
    __shared__ float c0s[HID];
    __shared__ float redm[4], reds[4];

    const int t  = __builtin_amdgcn_readfirstlane(type_index[b]);
    const int ni = __builtin_amdgcn_readfirstlane(node_index[0]);

    const float* At  = a1 + (size_t)t * (2 * FDIM * HID); // top    [FDIM][HID]
    const float* Ab  = At + FDIM * HID;                   // bottom [FDIM][HID]
    const float* a2t = a2 + t * HID;
    const float* xb  = x + (size_t)b * NODES * FDIM;
    const float* xw  = xb + (size_t)(w * 64) * FDIM;      // this wave's 64 rows

    // ---- c0[h] = sum_f x[b,ni,f] * At[f][h] (cooperative, tiny) ----
    {
        const float* x0 = xb + (size_t)ni * FDIM;
        const int f2 = tid >> 4;
        const int h  = tid & 15;
        float p = 0.f;
        #pragma unroll
        for (int j = 0; j < 8; ++j) {
            const int f = f2 * 8 + j;
            p = fmaf(x0[f], At[f * HID + h], p);
        }
        part[f2][h] = p;
    }
    __syncthreads();
    if (tid < 16) {
        float s = 0.f;
        #pragma unroll
        for (int g = 0; g < 16; ++g) s += part[g][tid];
        c0s[tid] = s;
    }
    __syncthreads();   // c0s ready; no more block barriers until softmax

    // ---- staging helpers (all indices compile-time after unroll) ----
    // chunk c, instr i: idx = i*64+lane -> row r = idx>>2, f4 = idx&3.
    // consecutive 4 lanes = one full 64B line; 16 lines per instruction.
    float4 st[4];
    auto load_chunk = [&](int c) {
        #pragma unroll
        for (int i = 0; i < 4; ++i) {
            const int idx = i * 64 + lane;
            const int r   = idx >> 2;
            const int f4  = idx & 3;
            st[i] = *(const float4*)(xw + (size_t)r * FDIM + c * CHF + f4 * 4);
        }
    };
    auto write_chunk = [&](int par) {
        float* dst = xl[w * 2 + par];
        #pragma unroll
        for (int i = 0; i < 4; ++i) {
            const int idx = i * 64 + lane;
            const int r   = idx >> 2;
            const int f4  = idx & 3;
            const int sl  = f4 ^ (r & 3);          // XOR swizzle
            *(float4*)&dst[r * CHF + sl * 4] = st[i];
        }
    };

    float acc[16];
    #pragma unroll
    for (int h = 0; h < 16; ++h) acc[h] = 0.f;

    // ---- prologue: chunk 0 into buffer 0 ----
    load_chunk(0);
    write_chunk(0);

    // ---- main loop: 8 chunks, wave-private double buffer ----
    #pragma unroll
    for (int c = 0; c < NCHK; ++c) {
        if (c + 1 < NCHK) load_chunk(c + 1);       // issue early (T14)

        const float* src = xl[w * 2 + (c & 1)];
        #pragma unroll
        for (int j = 0; j < 4; ++j) {
            const int sl = j ^ (lane & 3);          // swizzled read
            const float4 xv = *(const float4*)&src[lane * CHF + sl * 4];
            #pragma unroll
            for (int k = 0; k < 4; ++k) {
                const int f = c * CHF + j * 4 + k;  // compile-time
                const float xk = (k == 0) ? xv.x : (k == 1) ? xv.y
                               : (k == 2) ? xv.z : xv.w;
                const float* Wf = Ab + f * HID;     // uniform -> s_load
                #pragma unroll
                for (int h = 0; h < 16; ++h)
                    acc[h] = fmaf(xk, Wf[h], acc[h]);
            }
        }

        if (c + 1 < NCHK) write_chunk((c + 1) & 1); // vmcnt drain + ds_write
    }

    // ---- e = lrelu( sum_h lrelu(acc+c0) * a2 ), one per lane (its row) ----
    float e = 0.f;
    #pragma unroll
    for (int h = 0; h < 16; ++h) {
        float v = acc[h] + c0s[h];
        v = (v > 0.f) ? v : 0.01f * v;
        e = fmaf(v, a2t[h], e);
    }
    e = (e > 0.f) ? e : 0.01f * e;
    es[w * 64 + lane] = e;
    __syncthreads();

    // ---- masked softmax over 256 nodes ----
    const float ee  = es[tid];
    const float m   = adj[tid];
    float       val = (m > 0.f) ? ee : -INFINITY;

    float mx = val;
    #pragma unroll
    for (int off = 32; off; off >>= 1) mx = fmaxf(mx, __shfl_xor(mx, off));
    const int wid = tid >> 6;
    if ((tid & 63) == 0) redm[wid] = mx;
    __syncthreads();
    mx = fmaxf(fmaxf(redm[0], redm[1]), fmaxf(redm[2], redm[3]));

    float pr = (m > 0.f) ? __expf(ee - mx) : 0.f;
    float s = pr;
    #pragma unroll
    for (int off = 32; off; off >>= 1) s += __shfl_xor(s, off);
    if ((tid & 63) == 0) reds[wid] = s;
    __syncthreads();
    const float Z = reds[0] + reds[1] + reds[2] + reds[3];

    out[(size_t)b * NODES + tid] = pr / Z;
}

extern "C" void kernel_launch(void* const* d_in, const int* in_sizes, int n_in,
                              void* d_out, int out_size, void* d_ws, size_t ws_size,
                              hipStream_t stream) {
    const float* x   = (const float*)d_in[0];
    const float* a1  = (const float*)d_in[1];
    const float* a2  = (const float*)d_in[2];
    const float* adj = (const float*)d_in[3];
    const int*   ni  = (const int*)d_in[4];
    const int*   ti  = (const int*)d_in[5];
    float* out = (float*)d_out;

    mta_kernel<<<BATCH, NODES, 0, stream>>>(x, a1, a2, adj, ni, ti, out);
}

// Round 6
// 101.467 us; speedup vs baseline: 19.0391x; 1.7821x over previous
//
#include <hip/hip_runtime.h>
#include <math.h>

#define BATCH 4096
#define NODES 256
#define FDIM  128
#define HID   16

typedef __attribute__((ext_vector_type(8))) short short8;  // 8 bf16 (4 VGPRs)
typedef __attribute__((ext_vector_type(4))) float f32x4;   // MFMA C/D frag

// bf16 split helpers: x ~= hi + lo, each bf16 (truncation; residual-of-residual
// ~2^-16 relative -> near-fp32 accuracy with 3 MFMAs).
__device__ __forceinline__ short bf_trunc(float x) {
    return (short)(__float_as_uint(x) >> 16);
}
__device__ __forceinline__ float bf_back(short s) {
    return __uint_as_float(((unsigned)(unsigned short)s) << 16);
}
__device__ __forceinline__ void split8(float4 v0, float4 v1,
                                       short8& hi, short8& lo) {
    float v[8] = {v0.x, v0.y, v0.z, v0.w, v1.x, v1.y, v1.z, v1.w};
    #pragma unroll
    for (int j = 0; j < 8; ++j) {
        const short h = bf_trunc(v[j]);
        hi[j] = h;
        lo[j] = bf_trunc(v[j] - bf_back(h));
    }
}

// One block per batch element b; 256 threads = 4 waves; wave w owns rows
// 64w..64w+63 as 4 M-tiles of 16. GEMM shape per block: [256x128]x[128x16].
// Weights: B-fragments (hi+lo bf16) in 32 VGPRs, loaded ONCE per block --
// eliminates the per-f s_load/lgkm serial chain that capped R1/R5 at 2.9 TB/s.
// x: loaded global->VGPR directly in A-frag layout (16 rows x 32B per instr
// pair, lines fully consumed, 8 loads in flight per K-tile), split to bf16
// hi/lo, 3 MFMAs per tile (hi*hi + hi*lo + lo*hi ~= fp32).
// MFMA 16x16x32 layouts: A/B: idx=lane&15, k=(lane>>4)*8+j.
// D (m89-verified): col(h)=lane&15, row=(lane>>4)*4+reg.
__launch_bounds__(256, 2)
__global__ void mta_kernel(const float* __restrict__ x,
                           const float* __restrict__ a1,
                           const float* __restrict__ a2,
                           const float* __restrict__ adj,
                           const int*  __restrict__ node_index,
                           const int*  __restrict__ type_index,
                           float* __restrict__ out) {
    const int b    = blockIdx.x;
    const int tid  = threadIdx.x;
    const int lane = tid & 63;
    const int w    = tid >> 6;
    const int n    = lane & 15;   // h / fragment index
    const int g    = lane >> 4;   // k-group (0..3)

    __shared__ float es[NODES];
    __shared__ float part[16][17];
    __shared__ float c0s[HID];
    __shared__ float redm[4], reds[4];

    const int t  = __builtin_amdgcn_readfirstlane(type_index[b]);
    const int ni = __builtin_amdgcn_readfirstlane(node_index[0]);

    const float* At  = a1 + (size_t)t * (2 * FDIM * HID); // top    [FDIM][HID]
    const float* Ab  = At + FDIM * HID;                   // bottom [FDIM][HID]
    const float* a2t = a2 + t * HID;
    const float* xb  = x + (size_t)b * NODES * FDIM;

    // ---- c0[h] = sum_f x[b,ni,f] * At[f][h] (cooperative, fp32) ----
    {
        const float* x0 = xb + (size_t)ni * FDIM;
        const int f2 = tid >> 4;
        const int h  = tid & 15;
        float p = 0.f;
        #pragma unroll
        for (int j = 0; j < 8; ++j) {
            const int f = f2 * 8 + j;
            p = fmaf(x0[f], At[f * HID + h], p);
        }
        part[f2][h] = p;
    }
    __syncthreads();
    if (tid < 16) {
        float s = 0.f;
        #pragma unroll
        for (int gg = 0; gg < 16; ++gg) s += part[gg][tid];
        c0s[tid] = s;
    }
    __syncthreads();

    // ---- weight B-fragments: lane supplies W[k][n], k = kt*32 + g*8 + j ----
    short8 whi[4], wlo[4];
    #pragma unroll
    for (int kt = 0; kt < 4; ++kt) {
        float wv[8];
        #pragma unroll
        for (int j = 0; j < 8; ++j)
            wv[j] = Ab[(kt * 32 + g * 8 + j) * HID + n];   // L2/L3-hot, 8KB
        float4 w0 = {wv[0], wv[1], wv[2], wv[3]};
        float4 w1 = {wv[4], wv[5], wv[6], wv[7]};
        split8(w0, w1, whi[kt], wlo[kt]);
    }

    // ---- main GEMM: 4 K-tiles x 4 M-tiles, A from global, no barriers ----
    const int rowbase = w * 64;
    f32x4 acc[4];
    #pragma unroll
    for (int mt = 0; mt < 4; ++mt) acc[mt] = (f32x4){0.f, 0.f, 0.f, 0.f};

    #pragma unroll
    for (int kt = 0; kt < 4; ++kt) {
        // A-frag raw loads: lane reads x[row = mt*16+n][kt*32 + g*8 .. +8]
        float4 ra[4][2];
        #pragma unroll
        for (int mt = 0; mt < 4; ++mt) {
            const float* p = xb + (size_t)(rowbase + mt * 16 + n) * FDIM
                           + kt * 32 + g * 8;
            ra[mt][0] = *(const float4*)p;
            ra[mt][1] = *(const float4*)(p + 4);
        }
        #pragma unroll
        for (int mt = 0; mt < 4; ++mt) {
            short8 ahi, alo;
            split8(ra[mt][0], ra[mt][1], ahi, alo);
            acc[mt] = __builtin_amdgcn_mfma_f32_16x16x32_bf16(ahi, whi[kt], acc[mt], 0, 0, 0);
            acc[mt] = __builtin_amdgcn_mfma_f32_16x16x32_bf16(ahi, wlo[kt], acc[mt], 0, 0, 0);
            acc[mt] = __builtin_amdgcn_mfma_f32_16x16x32_bf16(alo, whi[kt], acc[mt], 0, 0, 0);
        }
    }

    // ---- epilogue: e[row] = lrelu( sum_h lrelu(acc+c0[h]) * a2[h] ) ----
    const float c0h = c0s[n];
    const float a2h = a2t[n];
    #pragma unroll
    for (int mt = 0; mt < 4; ++mt) {
        #pragma unroll
        for (int r = 0; r < 4; ++r) {
            float v = acc[mt][r] + c0h;
            v = (v > 0.f) ? v : 0.01f * v;
            float s = v * a2h;
            s += __shfl_xor(s, 1);
            s += __shfl_xor(s, 2);
            s += __shfl_xor(s, 4);
            s += __shfl_xor(s, 8);      // all 16 lanes of group hold sum_h
            float e = (s > 0.f) ? s : 0.01f * s;
            if (n == 0) es[rowbase + mt * 16 + g * 4 + r] = e;
        }
    }
    __syncthreads();

    // ---- masked softmax over 256 nodes ----
    const float ee  = es[tid];
    const float m   = adj[tid];
    float       val = (m > 0.f) ? ee : -INFINITY;

    float mx = val;
    #pragma unroll
    for (int off = 32; off; off >>= 1) mx = fmaxf(mx, __shfl_xor(mx, off));
    const int wid = tid >> 6;
    if ((tid & 63) == 0) redm[wid] = mx;
    __syncthreads();
    mx = fmaxf(fmaxf(redm[0], redm[1]), fmaxf(redm[2], redm[3]));

    float pr = (m > 0.f) ? __expf(ee - mx) : 0.f;
    float s = pr;
    #pragma unroll
    for (int off = 32; off; off >>= 1) s += __shfl_xor(s, off);
    if ((tid & 63) == 0) reds[wid] = s;
    __syncthreads();
    const float Z = reds[0] + reds[1] + reds[2] + reds[3];

    out[(size_t)b * NODES + tid] = pr / Z;
}

extern "C" void kernel_launch(void* const* d_in, const int* in_sizes, int n_in,
                              void* d_out, int out_size, void* d_ws, size_t ws_size,
                              hipStream_t stream) {
    const float* x   = (const float*)d_in[0];
    const float* a1  = (const float*)d_in[1];
    const float* a2  = (const float*)d_in[2];
    const float* adj = (const float*)d_in[3];
    const int*   ni  = (const int*)d_in[4];
    const int*   ti  = (const int*)d_in[5];
    float* out = (float*)d_out;

    mta_kernel<<<BATCH, NODES, 0, stream>>>(x, a1, a2, adj, ni, ti, out);
}